// Round 4
// baseline (908.879 us; speedup 1.0000x reference)
//
#include <hip/hip_runtime.h>

#define TT   512
#define DIN  2048
#define NH1  128
#define NH2  64
#define NB   64

typedef __attribute__((ext_vector_type(8))) __bf16 bf16x8;
typedef __attribute__((ext_vector_type(4))) __bf16 bf16x4;
typedef __attribute__((ext_vector_type(4))) float f32x4;

__device__ __forceinline__ float tanh_fast(float x) {
    x = fminf(fmaxf(x, -15.0f), 15.0f);
    float e = __expf(2.0f * x);
    return (e - 1.0f) / (e + 1.0f);
}

// Barrier WITHOUT vmcnt drain: LDS ordering only. Global loads stay in flight.
#define BAR() asm volatile("s_waitcnt lgkmcnt(0)\n\ts_barrier" ::: "memory")

// ---------------------------------------------------------------------------
// Kernel A: xp1 = x @ W_ih1^T + b  via 3-term bf16-split MFMA (~fp32 precision)
//   (unchanged — known-passing)
// ---------------------------------------------------------------------------
__global__ __launch_bounds__(256, 1) void xp1_gemm(const float* __restrict__ x,
                                                   const float* __restrict__ W,
                                                   const float* __restrict__ bih1,
                                                   const float* __restrict__ bhh1,
                                                   float* __restrict__ xp1) {
    __shared__ __align__(16) __bf16 wl[2][NH1][40];   // [plane][n][k pad 40]

    const int tid  = threadIdx.x;
    const int lane = tid & 63;
    const int wv   = tid >> 6;
    const int quad = lane >> 4;
    const int l16  = lane & 15;
    const int m0   = blockIdx.x * 128 + wv * 32;

    const int wr = tid >> 1;         // W stage: row
    const int wk = (tid & 1) * 16;   // W stage: k offset (16 fp32 per thread)

    float bias[8];
#pragma unroll
    for (int nt = 0; nt < 8; ++nt)
        bias[nt] = bih1[nt * 16 + l16] + bhh1[nt * 16 + l16];

    f32x4 acc[2][8];
#pragma unroll
    for (int ms = 0; ms < 2; ++ms)
#pragma unroll
        for (int nt = 0; nt < 8; ++nt)
            acc[ms][nt] = (f32x4){0.f, 0.f, 0.f, 0.f};

    const float* xr0 = x + (size_t)(m0 + l16) * DIN + quad * 8;
    const float* xr1 = x + (size_t)(m0 + 16 + l16) * DIN + quad * 8;
    const float* wp  = W + (size_t)wr * DIN + wk;

    // preload chunk 0
    float4 xa0 = *(const float4*)(xr0);
    float4 xb0 = *(const float4*)(xr0 + 4);
    float4 xa1 = *(const float4*)(xr1);
    float4 xb1 = *(const float4*)(xr1 + 4);
    float4 w0  = *(const float4*)(wp);
    float4 w1  = *(const float4*)(wp + 4);
    float4 w2  = *(const float4*)(wp + 8);
    float4 w3  = *(const float4*)(wp + 12);

    for (int kc = 0; kc < DIN; kc += 32) {
        // ---- convert & store W hi/lo planes (vmcnt wait auto-inserted)
        {
            float wf[16] = {w0.x, w0.y, w0.z, w0.w, w1.x, w1.y, w1.z, w1.w,
                            w2.x, w2.y, w2.z, w2.w, w3.x, w3.y, w3.z, w3.w};
            bf16x8 hv0, lv0, hv1, lv1;
#pragma unroll
            for (int j = 0; j < 8; ++j) {
                __bf16 h = (__bf16)wf[j];
                hv0[j] = h;
                lv0[j] = (__bf16)(wf[j] - (float)h);
            }
#pragma unroll
            for (int j = 0; j < 8; ++j) {
                __bf16 h = (__bf16)wf[8 + j];
                hv1[j] = h;
                lv1[j] = (__bf16)(wf[8 + j] - (float)h);
            }
            *(bf16x8*)&wl[0][wr][wk]     = hv0;
            *(bf16x8*)&wl[0][wr][wk + 8] = hv1;
            *(bf16x8*)&wl[1][wr][wk]     = lv0;
            *(bf16x8*)&wl[1][wr][wk + 8] = lv1;
        }
        BAR();

        // ---- convert current x to A-frags (before regs are overwritten)
        bf16x8 ah0, al0, ah1, al1;
        {
            float f0[8] = {xa0.x, xa0.y, xa0.z, xa0.w, xb0.x, xb0.y, xb0.z, xb0.w};
            float f1[8] = {xa1.x, xa1.y, xa1.z, xa1.w, xb1.x, xb1.y, xb1.z, xb1.w};
#pragma unroll
            for (int j = 0; j < 8; ++j) {
                __bf16 h0 = (__bf16)f0[j];
                ah0[j] = h0;
                al0[j] = (__bf16)(f0[j] - (float)h0);
                __bf16 h1 = (__bf16)f1[j];
                ah1[j] = h1;
                al1[j] = (__bf16)(f1[j] - (float)h1);
            }
        }

        // ---- prefetch next chunk (stays in flight through the MFMAs)
        if (kc + 32 < DIN) {
            xa0 = *(const float4*)(xr0 + kc + 32);
            xb0 = *(const float4*)(xr0 + kc + 36);
            xa1 = *(const float4*)(xr1 + kc + 32);
            xb1 = *(const float4*)(xr1 + kc + 36);
            w0  = *(const float4*)(wp + kc + 32);
            w1  = *(const float4*)(wp + kc + 36);
            w2  = *(const float4*)(wp + kc + 40);
            w3  = *(const float4*)(wp + kc + 44);
        }

        // ---- B-frags from LDS + 3-term MFMAs
#pragma unroll
        for (int nt = 0; nt < 8; ++nt) {
            bf16x8 bh = *(bf16x8*)&wl[0][nt * 16 + l16][quad * 8];
            bf16x8 bl = *(bf16x8*)&wl[1][nt * 16 + l16][quad * 8];
            acc[0][nt] = __builtin_amdgcn_mfma_f32_16x16x32_bf16(ah0, bh, acc[0][nt], 0, 0, 0);
            acc[0][nt] = __builtin_amdgcn_mfma_f32_16x16x32_bf16(al0, bh, acc[0][nt], 0, 0, 0);
            acc[0][nt] = __builtin_amdgcn_mfma_f32_16x16x32_bf16(ah0, bl, acc[0][nt], 0, 0, 0);
            acc[1][nt] = __builtin_amdgcn_mfma_f32_16x16x32_bf16(ah1, bh, acc[1][nt], 0, 0, 0);
            acc[1][nt] = __builtin_amdgcn_mfma_f32_16x16x32_bf16(al1, bh, acc[1][nt], 0, 0, 0);
            acc[1][nt] = __builtin_amdgcn_mfma_f32_16x16x32_bf16(ah1, bl, acc[1][nt], 0, 0, 0);
        }
        BAR();   // all reads done before next chunk's LDS overwrite
    }

    // ---- epilogue: C/D layout col=lane&15, row=quad*4+reg [m89-verified]
#pragma unroll
    for (int ms = 0; ms < 2; ++ms) {
        const int mb = m0 + ms * 16 + quad * 4;
#pragma unroll
        for (int nt = 0; nt < 8; ++nt) {
#pragma unroll
            for (int r = 0; r < 4; ++r)
                xp1[(size_t)(mb + r) * NH1 + nt * 16 + l16] = acc[ms][nt][r] + bias[nt];
        }
    }
}

// ---------------------------------------------------------------------------
// Kernel B v5 = v4 with the time off-by-one fixed. MFMA-batched scan:
// 4 blocks x 16 sequences, 4 waves. Per-step matvec = W(128x128) @ H(128x16)
// on the MFMA pipe (3-term bf16 hi/lo split, same trick as xp1_gemm).
// Step s computes h1[s] = tanh(xp1[TIME s-1] + Whh1 . h1[s-1])  <-- v4 bug:
// used time s (shifted input) -> absmax 2.86. Preload times 0,1; prefetch
// time s+1 for step s+2.
// Weights live in registers as A-frags; xp1 fp32 frag = exact MFMA C-init;
// xp2 frags pass step-to-step in registers; h1/h2 cross step via
// double-buffered bf16 hi/lo planes, XOR-swizzled (boff ^= (l16&7)<<4).
// One lgkm-only barrier per step.
// ---------------------------------------------------------------------------

__device__ __forceinline__ f32x4 mfma3(bf16x8 ah, bf16x8 al, bf16x8 bh, bf16x8 bl, f32x4 c) {
    c = __builtin_amdgcn_mfma_f32_16x16x32_bf16(ah, bh, c, 0, 0, 0);
    c = __builtin_amdgcn_mfma_f32_16x16x32_bf16(al, bh, c, 0, 0, 0);
    c = __builtin_amdgcn_mfma_f32_16x16x32_bf16(ah, bl, c, 0, 0, 0);
    return c;
}

__device__ __forceinline__ void tanh_split4(const f32x4& a, bf16x4& hv, bf16x4& lv) {
#pragma unroll
    for (int r = 0; r < 4; ++r) {
        float t = tanh_fast(a[r]);
        __bf16 h = (__bf16)t;
        hv[r] = h;
        lv[r] = (__bf16)(t - (float)h);
    }
}

// load 8 consecutive fp32 and split into bf16 hi/lo frags
__device__ __forceinline__ void load_split8(const float* p, bf16x8& hv, bf16x8& lv) {
    float4 u = *(const float4*)p;
    float4 v = *(const float4*)(p + 4);
    float f[8] = {u.x, u.y, u.z, u.w, v.x, v.y, v.z, v.w};
#pragma unroll
    for (int j = 0; j < 8; ++j) {
        __bf16 h = (__bf16)f[j];
        hv[j] = h;
        lv[j] = (__bf16)(f[j] - (float)h);
    }
}

template <int CUR>
__device__ __forceinline__ void scan_step(
        int s, int wv, int q, int l16, int sw, int s0,
        const float* __restrict__ xp1,
        __bf16 (&h1hi)[2][16][NH1], __bf16 (&h1lo)[2][16][NH1],
        __bf16 (&h2hi)[2][16][NH2], __bf16 (&h2lo)[2][16][NH2],
        const bf16x8 (&a1h)[2][4], const bf16x8 (&a1l)[2][4],
        const bf16x8 (&a2h)[4],    const bf16x8 (&a2l)[4],
        const bf16x8 (&a3h)[2],    const bf16x8 (&a3l)[2],
        const f32x4& b2f, f32x4& xpPrev, f32x4& x0, f32x4& x1) {
    const int NXT = CUR ^ 1;

    // ---- B-frags: h1[s-1] planes (swizzled, conflict-free)
    bf16x8 bh1[4], bl1[4];
    {
        const char* rbh = (const char*)&h1hi[CUR][l16][0];
        const char* rbl = (const char*)&h1lo[CUR][l16][0];
#pragma unroll
        for (int kt = 0; kt < 4; ++kt) {
            const int boff = (kt * 64 + q * 16) ^ sw;
            bh1[kt] = *(const bf16x8*)(rbh + boff);
            bl1[kt] = *(const bf16x8*)(rbl + boff);
        }
    }

    // ---- layer1: h1[s] = tanh(xp1[time s-1] + Whh1 . h1[s-1]); C-init = fp32 xp1 frag
    f32x4 acc0 = x0;
    f32x4 acc1 = x1;
#pragma unroll
    for (int kt = 0; kt < 4; ++kt)
        acc0 = mfma3(a1h[0][kt], a1l[0][kt], bh1[kt], bl1[kt], acc0);
#pragma unroll
    for (int kt = 0; kt < 4; ++kt)
        acc1 = mfma3(a1h[1][kt], a1l[1][kt], bh1[kt], bl1[kt], acc1);

    bf16x4 hv0, lv0, hv1, lv1;
    tanh_split4(acc0, hv0, lv0);
    tanh_split4(acc1, hv1, lv1);
    {
        char* wbh = (char*)&h1hi[NXT][l16][0];
        char* wbl = (char*)&h1lo[NXT][l16][0];
        const int w0 = ((wv * 32 + q * 4) * 2) ^ sw;
        const int w1 = ((wv * 32 + 16 + q * 4) * 2) ^ sw;
        *(bf16x4*)(wbh + w0) = hv0;
        *(bf16x4*)(wbl + w0) = lv0;
        *(bf16x4*)(wbh + w1) = hv1;
        *(bf16x4*)(wbl + w1) = lv1;
    }

    // ---- prefetch xp1 frag for step s+2 = time s+1 (BAR keeps vmcnt open)
    if (s + 2 <= TT) {
        const float* p = xp1 + ((size_t)(s0 + l16) * TT + (s + 1)) * NH1 + wv * 32 + q * 4;
        x0 = *(const f32x4*)p;
        x1 = *(const f32x4*)(p + 16);
    }

    // ---- layer2a: xp2[s-1] = b2 + Wih2 . h1[s-1]  (reuses bh1/bl1)
    f32x4 x2 = b2f;
#pragma unroll
    for (int kt = 0; kt < 4; ++kt)
        x2 = mfma3(a2h[kt], a2l[kt], bh1[kt], bl1[kt], x2);

    // ---- layer2b: h2[s-2] = tanh(xp2[s-2] + Whh2 . h2[s-3]); C-init = xp2 frag
    if (s >= 3) {
        bf16x8 bh2[2], bl2[2];
        const char* r2h = (const char*)&h2hi[CUR][l16][0];
        const char* r2l = (const char*)&h2lo[CUR][l16][0];
#pragma unroll
        for (int kt = 0; kt < 2; ++kt) {
            const int boff = (kt * 64 + q * 16) ^ sw;
            bh2[kt] = *(const bf16x8*)(r2h + boff);
            bl2[kt] = *(const bf16x8*)(r2l + boff);
        }
        f32x4 a2 = xpPrev;
#pragma unroll
        for (int kt = 0; kt < 2; ++kt)
            a2 = mfma3(a3h[kt], a3l[kt], bh2[kt], bl2[kt], a2);
        bf16x4 hv2, lv2;
        tanh_split4(a2, hv2, lv2);
        const int w2o = ((wv * 16 + q * 4) * 2) ^ sw;
        *(bf16x4*)((char*)&h2hi[NXT][l16][0] + w2o) = hv2;
        *(bf16x4*)((char*)&h2lo[NXT][l16][0] + w2o) = lv2;
    }
    xpPrev = x2;
    BAR();
}

__global__ __launch_bounds__(256, 1) void rnn_scan(
        const float* __restrict__ xp1,  const float* __restrict__ Whh1,
        const float* __restrict__ Wih2, const float* __restrict__ Whh2,
        const float* __restrict__ bih2, const float* __restrict__ bhh2,
        const float* __restrict__ Wfc1, const float* __restrict__ bfc1,
        const float* __restrict__ Wfc2, const float* __restrict__ bfc2,
        float* __restrict__ out) {
    __shared__ __align__(16) __bf16 h1hi[2][16][NH1];
    __shared__ __align__(16) __bf16 h1lo[2][16][NH1];
    __shared__ __align__(16) __bf16 h2hi[2][16][NH2];
    __shared__ __align__(16) __bf16 h2lo[2][16][NH2];
    __shared__ __align__(16) float  h2fin[16][NH2];

    const int tid  = threadIdx.x;
    const int lane = tid & 63;
    const int wv   = tid >> 6;
    const int q    = lane >> 4;
    const int l16  = lane & 15;
    const int sw   = (l16 & 7) << 4;          // plane-swizzle byte XOR
    const int s0   = blockIdx.x * 16;         // first sequence of this block

    // ---- weight A-frags (permanently in registers)
    bf16x8 a1h[2][4], a1l[2][4];              // Whh1 rows wv*32 + mt*16 + l16
#pragma unroll
    for (int mt = 0; mt < 2; ++mt)
#pragma unroll
        for (int kt = 0; kt < 4; ++kt)
            load_split8(Whh1 + (size_t)(wv * 32 + mt * 16 + l16) * NH1 + kt * 32 + q * 8,
                        a1h[mt][kt], a1l[mt][kt]);

    bf16x8 a2h[4], a2l[4];                    // Wih2 row wv*16 + l16, K=128
#pragma unroll
    for (int kt = 0; kt < 4; ++kt)
        load_split8(Wih2 + (size_t)(wv * 16 + l16) * NH1 + kt * 32 + q * 8,
                    a2h[kt], a2l[kt]);

    bf16x8 a3h[2], a3l[2];                    // Whh2 row wv*16 + l16, K=64
#pragma unroll
    for (int kt = 0; kt < 2; ++kt)
        load_split8(Whh2 + (size_t)(wv * 16 + l16) * NH2 + kt * 32 + q * 8,
                    a3h[kt], a3l[kt]);

    f32x4 b2f;                                // bias frag for xp2 rows wv*16+q*4..+3
    {
        float4 u = *(const float4*)&bih2[wv * 16 + q * 4];
        float4 v = *(const float4*)&bhh2[wv * 16 + q * 4];
        b2f = (f32x4){u.x + v.x, u.y + v.y, u.z + v.z, u.w + v.w};
    }

    // ---- zero h1/h2 planes buf0 (h1[0] = 0, h2[0] = 0)
    {
        bf16x8 z8;
#pragma unroll
        for (int j = 0; j < 8; ++j) z8[j] = (__bf16)0.0f;
        ((bf16x8*)&h1hi[0][0][0])[tid] = z8;   // 256*16B = 4096B = buf0
        ((bf16x8*)&h1lo[0][0][0])[tid] = z8;
        if (tid < 128) {
            ((bf16x8*)&h2hi[0][0][0])[tid] = z8;
            ((bf16x8*)&h2lo[0][0][0])[tid] = z8;
        }
    }

    // ---- preload xp1 frags: step 1 uses time 0, step 2 uses time 1
    f32x4 xA0, xA1, xB0, xB1;
    {
        const float* p1 = xp1 + ((size_t)(s0 + l16) * TT + 0) * NH1 + wv * 32 + q * 4;
        const float* p2 = xp1 + ((size_t)(s0 + l16) * TT + 1) * NH1 + wv * 32 + q * 4;
        xA0 = *(const f32x4*)p1;
        xA1 = *(const f32x4*)(p1 + 16);
        xB0 = *(const f32x4*)p2;
        xB1 = *(const f32x4*)(p2 + 16);
    }

    __syncthreads();

    f32x4 xpPrev = (f32x4){0.f, 0.f, 0.f, 0.f};

    // ---- main scan: steps 1..512 (odd step reads buf0, even reads buf1)
    for (int s = 1; s <= TT - 1; s += 2) {
        scan_step<0>(s,     wv, q, l16, sw, s0, xp1, h1hi, h1lo, h2hi, h2lo,
                     a1h, a1l, a2h, a2l, a3h, a3l, b2f, xpPrev, xA0, xA1);
        scan_step<1>(s + 1, wv, q, l16, sw, s0, xp1, h1hi, h1lo, h2hi, h2lo,
                     a1h, a1l, a2h, a2l, a3h, a3l, b2f, xpPrev, xB0, xB1);
    }

    // ---- tail s = 513 (cur = 0): layer2a -> xp2[512]; layer2b -> h2[511]
    {
        bf16x8 bh1[4], bl1[4];
        const char* rbh = (const char*)&h1hi[0][l16][0];
        const char* rbl = (const char*)&h1lo[0][l16][0];
#pragma unroll
        for (int kt = 0; kt < 4; ++kt) {
            const int boff = (kt * 64 + q * 16) ^ sw;
            bh1[kt] = *(const bf16x8*)(rbh + boff);
            bl1[kt] = *(const bf16x8*)(rbl + boff);
        }
        f32x4 x2 = b2f;
#pragma unroll
        for (int kt = 0; kt < 4; ++kt)
            x2 = mfma3(a2h[kt], a2l[kt], bh1[kt], bl1[kt], x2);

        bf16x8 bh2[2], bl2[2];
        const char* r2h = (const char*)&h2hi[0][l16][0];
        const char* r2l = (const char*)&h2lo[0][l16][0];
#pragma unroll
        for (int kt = 0; kt < 2; ++kt) {
            const int boff = (kt * 64 + q * 16) ^ sw;
            bh2[kt] = *(const bf16x8*)(r2h + boff);
            bl2[kt] = *(const bf16x8*)(r2l + boff);
        }
        f32x4 a2 = xpPrev;
#pragma unroll
        for (int kt = 0; kt < 2; ++kt)
            a2 = mfma3(a3h[kt], a3l[kt], bh2[kt], bl2[kt], a2);
        bf16x4 hv2, lv2;
        tanh_split4(a2, hv2, lv2);
        const int w2o = ((wv * 16 + q * 4) * 2) ^ sw;
        *(bf16x4*)((char*)&h2hi[1][l16][0] + w2o) = hv2;
        *(bf16x4*)((char*)&h2lo[1][l16][0] + w2o) = lv2;
        xpPrev = x2;
        BAR();
    }

    // ---- tail s = 514 (cur = 1): h2[512] -> h2fin (fp32)
    {
        bf16x8 bh2[2], bl2[2];
        const char* r2h = (const char*)&h2hi[1][l16][0];
        const char* r2l = (const char*)&h2lo[1][l16][0];
#pragma unroll
        for (int kt = 0; kt < 2; ++kt) {
            const int boff = (kt * 64 + q * 16) ^ sw;
            bh2[kt] = *(const bf16x8*)(r2h + boff);
            bl2[kt] = *(const bf16x8*)(r2l + boff);
        }
        f32x4 a2 = xpPrev;
#pragma unroll
        for (int kt = 0; kt < 2; ++kt)
            a2 = mfma3(a3h[kt], a3l[kt], bh2[kt], bl2[kt], a2);
        f32x4 tt;
#pragma unroll
        for (int r = 0; r < 4; ++r) tt[r] = tanh_fast(a2[r]);
        *(f32x4*)&h2fin[l16][wv * 16 + q * 4] = tt;
        BAR();
    }

    // ---- FC head: wave0 only. lane = c*16 + seq; c handles f-rows c*8..c*8+7
    if (wv == 0) {
        const int seq = lane & 15;
        const int c   = lane >> 4;
        float hreg[NH2];
#pragma unroll
        for (int i = 0; i < 16; ++i)
            *(f32x4*)&hreg[4 * i] = *(const f32x4*)&h2fin[seq][4 * i];

        float accv = 0.0f;
#pragma unroll
        for (int i = 0; i < 8; ++i) {
            const int r = c * 8 + i;
            float f = bfc1[r];
            const float* wr = Wfc1 + (size_t)r * NH2;
#pragma unroll
            for (int k4 = 0; k4 < 16; ++k4) {
                float4 wv4 = *(const float4*)(wr + 4 * k4);
                f = fmaf(wv4.x, hreg[4 * k4 + 0], f);
                f = fmaf(wv4.y, hreg[4 * k4 + 1], f);
                f = fmaf(wv4.z, hreg[4 * k4 + 2], f);
                f = fmaf(wv4.w, hreg[4 * k4 + 3], f);
            }
            accv += fmaxf(f, 0.0f) * Wfc2[r];
        }
        accv += __shfl_down(accv, 32);
        accv += __shfl_down(accv, 16);
        if (lane < 16) out[s0 + lane] = accv + bfc2[0];
    }
}

extern "C" void kernel_launch(void* const* d_in, const int* in_sizes, int n_in,
                              void* d_out, int out_size, void* d_ws, size_t ws_size,
                              hipStream_t stream) {
    const float* x     = (const float*)d_in[0];
    const float* Wih1  = (const float*)d_in[1];
    const float* Whh1  = (const float*)d_in[2];
    const float* bih1  = (const float*)d_in[3];
    const float* bhh1  = (const float*)d_in[4];
    const float* Wih2  = (const float*)d_in[5];
    const float* Whh2  = (const float*)d_in[6];
    const float* bih2  = (const float*)d_in[7];
    const float* bhh2  = (const float*)d_in[8];
    const float* Wfc1  = (const float*)d_in[9];
    const float* bfc1  = (const float*)d_in[10];
    const float* Wfc2  = (const float*)d_in[11];
    const float* bfc2  = (const float*)d_in[12];
    float* outp = (float*)d_out;

    float* xp1 = (float*)d_ws;   // 32768 x 128 fp32 = 16 MB

    xp1_gemm<<<dim3((NB * TT) / 128), dim3(256), 0, stream>>>(x, Wih1, bih1, bhh1, xp1);
    rnn_scan<<<dim3(NB / 16), dim3(256), 0, stream>>>(xp1, Whh1, Wih2, Whh2, bih2, bhh2,
                                                      Wfc1, bfc1, Wfc2, bfc2, outp);
}

// Round 5
// 892.759 us; speedup vs baseline: 1.0181x; 1.0181x over previous
//
#include <hip/hip_runtime.h>

#define TT   512
#define DIN  2048
#define NH1  128
#define NH2  64
#define NB   64

typedef __attribute__((ext_vector_type(8))) __bf16 bf16x8;
typedef __attribute__((ext_vector_type(4))) __bf16 bf16x4;
typedef __attribute__((ext_vector_type(4))) float f32x4;

__device__ __forceinline__ float tanh_fast(float x) {
    x = fminf(fmaxf(x, -15.0f), 15.0f);
    float e = __expf(2.0f * x);
    return (e - 1.0f) / (e + 1.0f);
}

// Barrier WITHOUT vmcnt drain: LDS ordering only. Global loads stay in flight.
#define BAR() asm volatile("s_waitcnt lgkmcnt(0)\n\ts_barrier" ::: "memory")

// ---------------------------------------------------------------------------
// Kernel A v2: xp1 = x @ W_ih1^T + b, 3-term bf16-split MFMA (~fp32 precision).
// r4 diagnosis: 380 us vs ~45 us HBM floor. At BM=128/BK=32 it ran 1 block/CU
// (launch_bounds(256,1)) -> every chunk's ~900-cyc HBM latency stalls the
// whole SIMD (compute/chunk ~500 cyc < latency), and 32B-per-row granularity
// thrashes DRAM rows. Fix: BM=64 -> grid 512, 2 blocks/CU (TLP hides vmcnt
// stalls); BK=64 -> 256B contiguous per row, half the barriers.
// ---------------------------------------------------------------------------
__global__ __launch_bounds__(256, 2) void xp1_gemm(const float* __restrict__ x,
                                                   const float* __restrict__ W,
                                                   const float* __restrict__ bih1,
                                                   const float* __restrict__ bhh1,
                                                   float* __restrict__ xp1) {
    __shared__ __align__(16) __bf16 wl[2][NH1][72];   // [plane][n][k 64 + pad 8]

    const int tid  = threadIdx.x;
    const int lane = tid & 63;
    const int wv   = tid >> 6;
    const int quad = lane >> 4;
    const int l16  = lane & 15;
    const int m0   = blockIdx.x * 64 + wv * 16;       // wave tile: 16 rows x 128 cols

    const int wr = tid >> 1;          // W stage: row 0..127
    const int wk = (tid & 1) * 32;    // W stage: col offset (32 fp32 per thread)

    float bias[8];
#pragma unroll
    for (int nt = 0; nt < 8; ++nt)
        bias[nt] = bih1[nt * 16 + l16] + bhh1[nt * 16 + l16];

    f32x4 acc[8];
#pragma unroll
    for (int nt = 0; nt < 8; ++nt)
        acc[nt] = (f32x4){0.f, 0.f, 0.f, 0.f};

    const float* xr = x + (size_t)(m0 + l16) * DIN;   // this lane's row
    const float* wp = W + (size_t)wr * DIN + wk;

    // preload chunk 0: x = two 32B segments (k-slice 0 at quad*8, slice 1 at 32+quad*8)
    float4 xa0 = *(const float4*)(xr + quad * 8);
    float4 xa1 = *(const float4*)(xr + quad * 8 + 4);
    float4 xb0 = *(const float4*)(xr + 32 + quad * 8);
    float4 xb1 = *(const float4*)(xr + 32 + quad * 8 + 4);
    float4 w4[8];
#pragma unroll
    for (int i = 0; i < 8; ++i) w4[i] = *(const float4*)(wp + 4 * i);

    for (int kc = 0; kc < DIN; kc += 64) {
        // ---- convert & store W hi/lo planes (vmcnt wait auto-inserted)
        {
            float wf[32];
#pragma unroll
            for (int i = 0; i < 8; ++i) {
                wf[4*i]   = w4[i].x; wf[4*i+1] = w4[i].y;
                wf[4*i+2] = w4[i].z; wf[4*i+3] = w4[i].w;
            }
#pragma unroll
            for (int g = 0; g < 4; ++g) {
                bf16x8 hv, lv;
#pragma unroll
                for (int j = 0; j < 8; ++j) {
                    __bf16 h = (__bf16)wf[8*g + j];
                    hv[j] = h;
                    lv[j] = (__bf16)(wf[8*g + j] - (float)h);
                }
                *(bf16x8*)&wl[0][wr][wk + 8*g] = hv;
                *(bf16x8*)&wl[1][wr][wk + 8*g] = lv;
            }
        }
        BAR();

        // ---- convert current x to A-frags (k-slice 0 and 1)
        bf16x8 ah0, al0, ah1, al1;
        {
            float f0[8] = {xa0.x, xa0.y, xa0.z, xa0.w, xa1.x, xa1.y, xa1.z, xa1.w};
            float f1[8] = {xb0.x, xb0.y, xb0.z, xb0.w, xb1.x, xb1.y, xb1.z, xb1.w};
#pragma unroll
            for (int j = 0; j < 8; ++j) {
                __bf16 h0 = (__bf16)f0[j];
                ah0[j] = h0;
                al0[j] = (__bf16)(f0[j] - (float)h0);
                __bf16 h1 = (__bf16)f1[j];
                ah1[j] = h1;
                al1[j] = (__bf16)(f1[j] - (float)h1);
            }
        }

        // ---- prefetch next chunk (stays in flight through the MFMAs)
        if (kc + 64 < DIN) {
            xa0 = *(const float4*)(xr + kc + 64 + quad * 8);
            xa1 = *(const float4*)(xr + kc + 64 + quad * 8 + 4);
            xb0 = *(const float4*)(xr + kc + 96 + quad * 8);
            xb1 = *(const float4*)(xr + kc + 96 + quad * 8 + 4);
#pragma unroll
            for (int i = 0; i < 8; ++i) w4[i] = *(const float4*)(wp + kc + 64 + 4 * i);
        }

        // ---- B-frags from LDS + 3-term MFMAs (two k-slices per chunk)
#pragma unroll
        for (int nt = 0; nt < 8; ++nt) {
            bf16x8 bh0 = *(bf16x8*)&wl[0][nt * 16 + l16][quad * 8];
            bf16x8 bl0 = *(bf16x8*)&wl[1][nt * 16 + l16][quad * 8];
            bf16x8 bh1v = *(bf16x8*)&wl[0][nt * 16 + l16][32 + quad * 8];
            bf16x8 bl1v = *(bf16x8*)&wl[1][nt * 16 + l16][32 + quad * 8];
            acc[nt] = __builtin_amdgcn_mfma_f32_16x16x32_bf16(ah0, bh0, acc[nt], 0, 0, 0);
            acc[nt] = __builtin_amdgcn_mfma_f32_16x16x32_bf16(al0, bh0, acc[nt], 0, 0, 0);
            acc[nt] = __builtin_amdgcn_mfma_f32_16x16x32_bf16(ah0, bl0, acc[nt], 0, 0, 0);
            acc[nt] = __builtin_amdgcn_mfma_f32_16x16x32_bf16(ah1, bh1v, acc[nt], 0, 0, 0);
            acc[nt] = __builtin_amdgcn_mfma_f32_16x16x32_bf16(al1, bh1v, acc[nt], 0, 0, 0);
            acc[nt] = __builtin_amdgcn_mfma_f32_16x16x32_bf16(ah1, bl1v, acc[nt], 0, 0, 0);
        }
        BAR();   // all reads done before next chunk's LDS overwrite
    }

    // ---- epilogue: C/D layout col=lane&15, row=quad*4+reg [m89-verified]
    const int mb = m0 + quad * 4;
#pragma unroll
    for (int nt = 0; nt < 8; ++nt) {
#pragma unroll
        for (int r = 0; r < 4; ++r)
            xp1[(size_t)(mb + r) * NH1 + nt * 16 + l16] = acc[nt][r] + bias[nt];
    }
}

// ---------------------------------------------------------------------------
// Kernel B v6: MFMA-batched scan (structure of v5, numerically validated).
// r4 diagnosis: 2460 cyc/step with per-CU VALUBusy ~53% -> ~200 regs of
// operands vs VGPR_Count=128 => AGPR shuttling + 12-deep MFMA chains.
// Fixes: (1) 2-term split — drop W-lo planes (Whi*hhi + Whi*hlo). W becomes
// effectively bf16: systematic ~2^-9 perturbation, est. final err <=5e-3
// vs 4.9e-2 threshold. Weight regs 112->56, MFMAs 42->28.
// (2) hi/lo terms in SEPARATE accumulator chains (depth 12->4), add at end.
// (3) all 12 ds_read_b128 hoisted to step top (h2 bufs both zeroed at init
// so the unconditional read is clean).
// ---------------------------------------------------------------------------

__device__ __forceinline__ void tanh_split4(const f32x4& a, bf16x4& hv, bf16x4& lv) {
#pragma unroll
    for (int r = 0; r < 4; ++r) {
        float t = tanh_fast(a[r]);
        __bf16 h = (__bf16)t;
        hv[r] = h;
        lv[r] = (__bf16)(t - (float)h);
    }
}

// load 8 consecutive fp32 and round to bf16 (hi plane only)
__device__ __forceinline__ void load_hi8(const float* p, bf16x8& hv) {
    float4 u = *(const float4*)p;
    float4 v = *(const float4*)(p + 4);
    float f[8] = {u.x, u.y, u.z, u.w, v.x, v.y, v.z, v.w};
#pragma unroll
    for (int j = 0; j < 8; ++j) hv[j] = (__bf16)f[j];
}

template <int CUR>
__device__ __forceinline__ void scan_step(
        int s, int wv, int q, int l16, int sw, int s0,
        const float* __restrict__ xp1,
        __bf16 (&h1hi)[2][16][NH1], __bf16 (&h1lo)[2][16][NH1],
        __bf16 (&h2hi)[2][16][NH2], __bf16 (&h2lo)[2][16][NH2],
        const bf16x8 (&a1h)[2][4], const bf16x8 (&a2h)[4], const bf16x8 (&a3h)[2],
        const f32x4& b2f, f32x4& xpPrev, f32x4& x0, f32x4& x1) {
    const int NXT = CUR ^ 1;

    // ---- ALL plane reads issued up front (12 ds_read_b128 back-to-back)
    bf16x8 bh1[4], bl1[4], bh2[2], bl2[2];
    {
        const char* rbh = (const char*)&h1hi[CUR][l16][0];
        const char* rbl = (const char*)&h1lo[CUR][l16][0];
#pragma unroll
        for (int kt = 0; kt < 4; ++kt) {
            const int boff = (kt * 64 + q * 16) ^ sw;
            bh1[kt] = *(const bf16x8*)(rbh + boff);
            bl1[kt] = *(const bf16x8*)(rbl + boff);
        }
        const char* r2h = (const char*)&h2hi[CUR][l16][0];
        const char* r2l = (const char*)&h2lo[CUR][l16][0];
#pragma unroll
        for (int kt = 0; kt < 2; ++kt) {
            const int boff = (kt * 64 + q * 16) ^ sw;
            bh2[kt] = *(const bf16x8*)(r2h + boff);
            bl2[kt] = *(const bf16x8*)(r2l + boff);
        }
    }

    // ---- layer1: h1[s] = tanh(xp1[time s-1] + Whh1.h1[s-1]); two 4-chains/tile
    f32x4 sA = x0, sB = (f32x4){0.f, 0.f, 0.f, 0.f};
    f32x4 tA = x1, tB = (f32x4){0.f, 0.f, 0.f, 0.f};
#pragma unroll
    for (int kt = 0; kt < 4; ++kt) {
        sA = __builtin_amdgcn_mfma_f32_16x16x32_bf16(a1h[0][kt], bh1[kt], sA, 0, 0, 0);
        sB = __builtin_amdgcn_mfma_f32_16x16x32_bf16(a1h[0][kt], bl1[kt], sB, 0, 0, 0);
        tA = __builtin_amdgcn_mfma_f32_16x16x32_bf16(a1h[1][kt], bh1[kt], tA, 0, 0, 0);
        tB = __builtin_amdgcn_mfma_f32_16x16x32_bf16(a1h[1][kt], bl1[kt], tB, 0, 0, 0);
    }
    f32x4 acc0, acc1;
#pragma unroll
    for (int r = 0; r < 4; ++r) { acc0[r] = sA[r] + sB[r]; acc1[r] = tA[r] + tB[r]; }

    bf16x4 hv0, lv0, hv1, lv1;
    tanh_split4(acc0, hv0, lv0);
    tanh_split4(acc1, hv1, lv1);
    {
        char* wbh = (char*)&h1hi[NXT][l16][0];
        char* wbl = (char*)&h1lo[NXT][l16][0];
        const int w0 = ((wv * 32 + q * 4) * 2) ^ sw;
        const int w1 = ((wv * 32 + 16 + q * 4) * 2) ^ sw;
        *(bf16x4*)(wbh + w0) = hv0;
        *(bf16x4*)(wbl + w0) = lv0;
        *(bf16x4*)(wbh + w1) = hv1;
        *(bf16x4*)(wbl + w1) = lv1;
    }

    // ---- prefetch xp1 frag for step s+2 = time s+1 (BAR keeps vmcnt open)
    if (s + 2 <= TT) {
        const float* p = xp1 + ((size_t)(s0 + l16) * TT + (s + 1)) * NH1 + wv * 32 + q * 4;
        x0 = *(const f32x4*)p;
        x1 = *(const f32x4*)(p + 16);
    }

    // ---- layer2a: xp2[s-1] = b2 + Wih2.h1[s-1]  (two 4-chains)
    f32x4 pA = b2f, pB = (f32x4){0.f, 0.f, 0.f, 0.f};
#pragma unroll
    for (int kt = 0; kt < 4; ++kt) {
        pA = __builtin_amdgcn_mfma_f32_16x16x32_bf16(a2h[kt], bh1[kt], pA, 0, 0, 0);
        pB = __builtin_amdgcn_mfma_f32_16x16x32_bf16(a2h[kt], bl1[kt], pB, 0, 0, 0);
    }
    f32x4 x2;
#pragma unroll
    for (int r = 0; r < 4; ++r) x2[r] = pA[r] + pB[r];

    // ---- layer2b: h2[s-2] = tanh(xp2[s-2] + Whh2.h2[s-3])  (two 2-chains)
    if (s >= 3) {
        f32x4 uA = xpPrev, uB = (f32x4){0.f, 0.f, 0.f, 0.f};
#pragma unroll
        for (int kt = 0; kt < 2; ++kt) {
            uA = __builtin_amdgcn_mfma_f32_16x16x32_bf16(a3h[kt], bh2[kt], uA, 0, 0, 0);
            uB = __builtin_amdgcn_mfma_f32_16x16x32_bf16(a3h[kt], bl2[kt], uB, 0, 0, 0);
        }
        f32x4 pre;
#pragma unroll
        for (int r = 0; r < 4; ++r) pre[r] = uA[r] + uB[r];
        bf16x4 hv2, lv2;
        tanh_split4(pre, hv2, lv2);
        const int w2o = ((wv * 16 + q * 4) * 2) ^ sw;
        *(bf16x4*)((char*)&h2hi[NXT][l16][0] + w2o) = hv2;
        *(bf16x4*)((char*)&h2lo[NXT][l16][0] + w2o) = lv2;
    }
    xpPrev = x2;
    BAR();
}

__global__ __launch_bounds__(256, 1) void rnn_scan(
        const float* __restrict__ xp1,  const float* __restrict__ Whh1,
        const float* __restrict__ Wih2, const float* __restrict__ Whh2,
        const float* __restrict__ bih2, const float* __restrict__ bhh2,
        const float* __restrict__ Wfc1, const float* __restrict__ bfc1,
        const float* __restrict__ Wfc2, const float* __restrict__ bfc2,
        float* __restrict__ out) {
    __shared__ __align__(16) __bf16 h1hi[2][16][NH1];
    __shared__ __align__(16) __bf16 h1lo[2][16][NH1];
    __shared__ __align__(16) __bf16 h2hi[2][16][NH2];
    __shared__ __align__(16) __bf16 h2lo[2][16][NH2];
    __shared__ __align__(16) float  h2fin[16][NH2];

    const int tid  = threadIdx.x;
    const int lane = tid & 63;
    const int wv   = tid >> 6;
    const int q    = lane >> 4;
    const int l16  = lane & 15;
    const int sw   = (l16 & 7) << 4;          // plane-swizzle byte XOR
    const int s0   = blockIdx.x * 16;         // first sequence of this block

    // ---- weight A-frags, hi plane only (2-term scheme), resident in regs
    bf16x8 a1h[2][4];                         // Whh1 rows wv*32 + mt*16 + l16
#pragma unroll
    for (int mt = 0; mt < 2; ++mt)
#pragma unroll
        for (int kt = 0; kt < 4; ++kt)
            load_hi8(Whh1 + (size_t)(wv * 32 + mt * 16 + l16) * NH1 + kt * 32 + q * 8,
                     a1h[mt][kt]);

    bf16x8 a2h[4];                            // Wih2 row wv*16 + l16, K=128
#pragma unroll
    for (int kt = 0; kt < 4; ++kt)
        load_hi8(Wih2 + (size_t)(wv * 16 + l16) * NH1 + kt * 32 + q * 8, a2h[kt]);

    bf16x8 a3h[2];                            // Whh2 row wv*16 + l16, K=64
#pragma unroll
    for (int kt = 0; kt < 2; ++kt)
        load_hi8(Whh2 + (size_t)(wv * 16 + l16) * NH2 + kt * 32 + q * 8, a3h[kt]);

    f32x4 b2f;                                // bias frag for xp2 rows wv*16+q*4..+3
    {
        float4 u = *(const float4*)&bih2[wv * 16 + q * 4];
        float4 v = *(const float4*)&bhh2[wv * 16 + q * 4];
        b2f = (f32x4){u.x + v.x, u.y + v.y, u.z + v.z, u.w + v.w};
    }

    // ---- zero h1 buf0 and BOTH h2 buffers (unconditional reads need buf1 clean)
    {
        bf16x8 z8;
#pragma unroll
        for (int j = 0; j < 8; ++j) z8[j] = (__bf16)0.0f;
        ((bf16x8*)&h1hi[0][0][0])[tid] = z8;   // h1 buf0: 2048 bf16 = 256 frags
        ((bf16x8*)&h1lo[0][0][0])[tid] = z8;
        ((bf16x8*)&h2hi[0][0][0])[tid] = z8;   // h2 both bufs: 2048 bf16 = 256 frags
        ((bf16x8*)&h2lo[0][0][0])[tid] = z8;
    }

    // ---- preload xp1 frags: step 1 uses time 0, step 2 uses time 1
    f32x4 xA0, xA1, xB0, xB1;
    {
        const float* p1 = xp1 + ((size_t)(s0 + l16) * TT + 0) * NH1 + wv * 32 + q * 4;
        const float* p2 = xp1 + ((size_t)(s0 + l16) * TT + 1) * NH1 + wv * 32 + q * 4;
        xA0 = *(const f32x4*)p1;
        xA1 = *(const f32x4*)(p1 + 16);
        xB0 = *(const f32x4*)p2;
        xB1 = *(const f32x4*)(p2 + 16);
    }

    __syncthreads();

    f32x4 xpPrev = (f32x4){0.f, 0.f, 0.f, 0.f};

    // ---- main scan: steps 1..512 (odd step reads buf0, even reads buf1)
    for (int s = 1; s <= TT - 1; s += 2) {
        scan_step<0>(s,     wv, q, l16, sw, s0, xp1, h1hi, h1lo, h2hi, h2lo,
                     a1h, a2h, a3h, b2f, xpPrev, xA0, xA1);
        scan_step<1>(s + 1, wv, q, l16, sw, s0, xp1, h1hi, h1lo, h2hi, h2lo,
                     a1h, a2h, a3h, b2f, xpPrev, xB0, xB1);
    }

    // ---- tail s = 513 (cur = 0): layer2a -> xp2[512]; layer2b -> h2[511]
    {
        bf16x8 bh1[4], bl1[4], bh2[2], bl2[2];
        const char* rbh = (const char*)&h1hi[0][l16][0];
        const char* rbl = (const char*)&h1lo[0][l16][0];
#pragma unroll
        for (int kt = 0; kt < 4; ++kt) {
            const int boff = (kt * 64 + q * 16) ^ sw;
            bh1[kt] = *(const bf16x8*)(rbh + boff);
            bl1[kt] = *(const bf16x8*)(rbl + boff);
        }
        const char* r2h = (const char*)&h2hi[0][l16][0];
        const char* r2l = (const char*)&h2lo[0][l16][0];
#pragma unroll
        for (int kt = 0; kt < 2; ++kt) {
            const int boff = (kt * 64 + q * 16) ^ sw;
            bh2[kt] = *(const bf16x8*)(r2h + boff);
            bl2[kt] = *(const bf16x8*)(r2l + boff);
        }
        f32x4 pA = b2f, pB = (f32x4){0.f, 0.f, 0.f, 0.f};
#pragma unroll
        for (int kt = 0; kt < 4; ++kt) {
            pA = __builtin_amdgcn_mfma_f32_16x16x32_bf16(a2h[kt], bh1[kt], pA, 0, 0, 0);
            pB = __builtin_amdgcn_mfma_f32_16x16x32_bf16(a2h[kt], bl1[kt], pB, 0, 0, 0);
        }
        f32x4 x2;
#pragma unroll
        for (int r = 0; r < 4; ++r) x2[r] = pA[r] + pB[r];

        f32x4 uA = xpPrev, uB = (f32x4){0.f, 0.f, 0.f, 0.f};
#pragma unroll
        for (int kt = 0; kt < 2; ++kt) {
            uA = __builtin_amdgcn_mfma_f32_16x16x32_bf16(a3h[kt], bh2[kt], uA, 0, 0, 0);
            uB = __builtin_amdgcn_mfma_f32_16x16x32_bf16(a3h[kt], bl2[kt], uB, 0, 0, 0);
        }
        f32x4 pre;
#pragma unroll
        for (int r = 0; r < 4; ++r) pre[r] = uA[r] + uB[r];
        bf16x4 hv2, lv2;
        tanh_split4(pre, hv2, lv2);
        const int w2o = ((wv * 16 + q * 4) * 2) ^ sw;
        *(bf16x4*)((char*)&h2hi[1][l16][0] + w2o) = hv2;
        *(bf16x4*)((char*)&h2lo[1][l16][0] + w2o) = lv2;
        xpPrev = x2;
        BAR();
    }

    // ---- tail s = 514 (cur = 1): h2[512] -> h2fin (fp32)
    {
        bf16x8 bh2[2], bl2[2];
        const char* r2h = (const char*)&h2hi[1][l16][0];
        const char* r2l = (const char*)&h2lo[1][l16][0];
#pragma unroll
        for (int kt = 0; kt < 2; ++kt) {
            const int boff = (kt * 64 + q * 16) ^ sw;
            bh2[kt] = *(const bf16x8*)(r2h + boff);
            bl2[kt] = *(const bf16x8*)(r2l + boff);
        }
        f32x4 uA = xpPrev, uB = (f32x4){0.f, 0.f, 0.f, 0.f};
#pragma unroll
        for (int kt = 0; kt < 2; ++kt) {
            uA = __builtin_amdgcn_mfma_f32_16x16x32_bf16(a3h[kt], bh2[kt], uA, 0, 0, 0);
            uB = __builtin_amdgcn_mfma_f32_16x16x32_bf16(a3h[kt], bl2[kt], uB, 0, 0, 0);
        }
        f32x4 tt;
#pragma unroll
        for (int r = 0; r < 4; ++r) tt[r] = tanh_fast(uA[r] + uB[r]);
        *(f32x4*)&h2fin[l16][wv * 16 + q * 4] = tt;
        BAR();
    }

    // ---- FC head: wave0 only. lane = c*16 + seq; c handles f-rows c*8..c*8+7
    if (wv == 0) {
        const int seq = lane & 15;
        const int c   = lane >> 4;
        float hreg[NH2];
#pragma unroll
        for (int i = 0; i < 16; ++i)
            *(f32x4*)&hreg[4 * i] = *(const f32x4*)&h2fin[seq][4 * i];

        float accv = 0.0f;
#pragma unroll
        for (int i = 0; i < 8; ++i) {
            const int r = c * 8 + i;
            float f = bfc1[r];
            const float* wr = Wfc1 + (size_t)r * NH2;
#pragma unroll
            for (int k4 = 0; k4 < 16; ++k4) {
                float4 wv4 = *(const float4*)(wr + 4 * k4);
                f = fmaf(wv4.x, hreg[4 * k4 + 0], f);
                f = fmaf(wv4.y, hreg[4 * k4 + 1], f);
                f = fmaf(wv4.z, hreg[4 * k4 + 2], f);
                f = fmaf(wv4.w, hreg[4 * k4 + 3], f);
            }
            accv += fmaxf(f, 0.0f) * Wfc2[r];
        }
        accv += __shfl_down(accv, 32);
        accv += __shfl_down(accv, 16);
        if (lane < 16) out[s0 + lane] = accv + bfc2[0];
    }
}

extern "C" void kernel_launch(void* const* d_in, const int* in_sizes, int n_in,
                              void* d_out, int out_size, void* d_ws, size_t ws_size,
                              hipStream_t stream) {
    const float* x     = (const float*)d_in[0];
    const float* Wih1  = (const float*)d_in[1];
    const float* Whh1  = (const float*)d_in[2];
    const float* bih1  = (const float*)d_in[3];
    const float* bhh1  = (const float*)d_in[4];
    const float* Wih2  = (const float*)d_in[5];
    const float* Whh2  = (const float*)d_in[6];
    const float* bih2  = (const float*)d_in[7];
    const float* bhh2  = (const float*)d_in[8];
    const float* Wfc1  = (const float*)d_in[9];
    const float* bfc1  = (const float*)d_in[10];
    const float* Wfc2  = (const float*)d_in[11];
    const float* bfc2  = (const float*)d_in[12];
    float* outp = (float*)d_out;

    float* xp1 = (float*)d_ws;   // 32768 x 128 fp32 = 16 MB

    xp1_gemm<<<dim3((NB * TT) / 64), dim3(256), 0, stream>>>(x, Wih1, bih1, bhh1, xp1);
    rnn_scan<<<dim3(NB / 16), dim3(256), 0, stream>>>(xp1, Whh1, Wih2, Whh2, bih2, bhh2,
                                                      Wfc1, bfc1, Wfc2, bfc2, outp);
}